// Round 5
// baseline (5919.081 us; speedup 1.0000x reference)
//
#include <hip/hip_runtime.h>
#include <math.h>

#define N 64
#define LSTR 66   // padded LDS row stride (floats): banks (2j+c)%32 -> worst 2-way (free)
typedef float f32x2 __attribute__((ext_vector_type(2)));

struct Smem {
    float mat[N * LSTR];   // matrix staging / transpose buffer
    float nbuf[2 * N];     // per-sweep norm partials
    float obuf[2][2 * N];  // per-round pair-dot partials, double-buffered by parity
    float coefbuf[N];      // spectral coefficients
};

__device__ __forceinline__ float bperm(int byteaddr, float v) {
    return __int_as_float(__builtin_amdgcn_ds_bpermute(byteaddr, __float_as_int(v)));
}

__device__ __forceinline__ float norm2half(const f32x2 (&g)[16]) {
    f32x2 a = {0.f, 0.f}, b = {0.f, 0.f};
#pragma unroll
    for (int i = 0; i < 16; i += 2) { a = g[i] * g[i] + a; b = g[i + 1] * g[i + 1] + b; }
    f32x2 s = a + b;
    return s.x + s.y;
}

// Parallel one-sided Jacobi; matrix split across the block's 2 waves.
// Wave w owns rows [32w,32w+32); lane j owns column j's half (g[16] f32x2).
// Pair dots are completed via LDS partial exchange; both waves add partials
// in the same order -> o/d/c/s streams bitwise-identical -> all branches
// (continue / sweep break) are uniform across the block. 1 barrier per round
// (obuf parity double-buffer removes the WAR barrier).
__device__ float jacobi_split(f32x2 (&g)[16], int lane, int wid, Smem& S, int max_sweeps) {
    float d = 0.f;
#pragma clang loop unroll(disable)
    for (int s = 0; s < max_sweeps; ++s) {
        S.nbuf[wid * N + lane] = norm2half(g);   // exact norms at sweep start
        __syncthreads();
        d = S.nbuf[lane] + S.nbuf[N + lane];
        __syncthreads();
        int anybad = 0;
#pragma clang loop unroll(disable)
        for (int m = 1; m < N; ++m) {
            int paddr = (lane ^ m) << 2;
            f32x2 t[16];
#pragma unroll
            for (int i = 0; i < 16; ++i) {
                t[i].x = bperm(paddr, g[i].x);
                t[i].y = bperm(paddr, g[i].y);
            }
            f32x2 oa = {0.f, 0.f}, ob = {0.f, 0.f};
#pragma unroll
            for (int i = 0; i < 16; i += 2) { oa = g[i] * t[i] + oa; ob = g[i + 1] * t[i + 1] + ob; }
            f32x2 os = oa + ob;
            float doth = bperm(paddr, d);
            int p = m & 1;
            S.obuf[p][wid * N + lane] = os.x + os.y;
            __syncthreads();
            float o = S.obuf[p][lane] + S.obuf[p][N + lane];
            bool is_lo = lane < (lane ^ m);
            float dp = is_lo ? d : doth;
            float dq = is_lo ? doth : d;
            int roundbad = __any(o * o > 1e-11f * dp * dq);
            anybad |= roundbad;
            if (!roundbad) continue;   // uniform: skip c,s + update for converged rounds
            bool skip = (o * o) <= (1e-24f * dp * dq);
            float osafe = skip ? 1.0f : o;
            // small-|t| root of t^2 + 2*theta*t - 1 = 0, theta = (dq-dp)/(2o)
            float theta = (dq - dp) / (2.0f * osafe);
            float tt = -copysignf(1.0f, theta) /
                       (fabsf(theta) + sqrtf(fmaf(theta, theta, 1.0f)));
            float cc = rsqrtf(fmaf(tt, tt, 1.0f));
            float sv = tt * cc;
            cc = skip ? 1.0f : cc;
            sv = skip ? 0.0f : sv;
            float c2 = cc * cc, s2 = sv * sv, cso = 2.0f * cc * sv * o;
            d = is_lo ? fmaf(c2, dp, fmaf(s2, dq, cso))
                      : fmaf(s2, dp, fmaf(c2, dq, -cso));
            d = fmaxf(d, 1e-30f);
            float ss = is_lo ? sv : -sv;
            f32x2 cv = {cc, cc}, sv2 = {ss, ss};
#pragma unroll
            for (int i = 0; i < 16; ++i) g[i] = sv2 * t[i] + cv * g[i];
        }
        if (!__any(anybad)) break;   // uniform across both waves
    }
    // final exact norm (cross-wave)
    S.nbuf[wid * N + lane] = norm2half(g);
    __syncthreads();
    d = S.nbuf[lane] + S.nbuf[N + lane];
    __syncthreads();
    return d;
}

// out = sum_k coef_k * g_k g_k^T, rows [32w,32w+32), column `lane` (coalesced).
__device__ void recon_store(const f32x2 (&g)[16], float coef, int lane, int wid,
                            Smem& S, float* __restrict__ outp) {
    int row0 = wid * 32;
    if (wid == 0) S.coefbuf[lane] = coef;   // identical on both waves
    // column-major G into LDS: mat[k*LSTR + r] = G[r][k]
#pragma unroll
    for (int i = 0; i < 16; ++i)
        *(f32x2*)&S.mat[lane * LSTR + row0 + 2 * i] = g[i];
    __syncthreads();
    f32x2 acc[16];
#pragma unroll
    for (int i = 0; i < 16; ++i) acc[i] = (f32x2){0.f, 0.f};
#pragma clang loop unroll(disable)
    for (int k = 0; k < N; ++k) {
        float wk = S.coefbuf[k] * S.mat[k * LSTR + lane];   // coef_k * G[lane][k]
        f32x2 wv = {wk, wk};
        const f32x2* col = (const f32x2*)&S.mat[k * LSTR + row0];  // broadcast b64 reads
#pragma unroll
        for (int i = 0; i < 16; ++i) acc[i] = col[i] * wv + acc[i];
    }
#pragma unroll
    for (int i = 0; i < 16; ++i) {
        outp[(row0 + 2 * i) * N + lane]     = acc[i].x;
        outp[(row0 + 2 * i + 1) * N + lane] = acc[i].y;
    }
}

// Kernel A: R_c = ((1-psi) W_c + psi I)^{-1/2}; one block (2 waves) per channel.
__global__ __launch_bounds__(128, 4) void prep_R(const float* __restrict__ wgt,
                                                 float* __restrict__ Rws) {
    __shared__ Smem S;
    int c = blockIdx.x;
    int tid = threadIdx.x, wid = tid >> 6, lane = tid & 63;
    int row0 = wid * 32;
    const float* W = wgt + (size_t)c * (N * N);
    f32x2 g[16];
#pragma unroll
    for (int i = 0; i < 16; ++i) {
        g[i].x = 0.999f * W[(row0 + 2 * i) * N + lane]     + ((row0 + 2 * i)     == lane ? 0.001f : 0.f);
        g[i].y = 0.999f * W[(row0 + 2 * i + 1) * N + lane] + ((row0 + 2 * i + 1) == lane ? 0.001f : 0.f);
    }
    float d = jacobi_split(g, lane, wid, S, 15);
    float coef = sqrtf(rsqrtf(d)) / d;   // f = lambda^{-1/2}, lambda = sqrt(d) -> coef = d^{-5/4}
    recon_store(g, coef, lane, wid, S, Rws + (size_t)c * (N * N));
}

// Kernel B: per (b,c): M = R_c Theta_b R_c -> symmetrize -> recondition -> log.
__global__ __launch_bounds__(128, 4) void tangent_log(const float* __restrict__ inp,
                                                      const float* __restrict__ Rws,
                                                      float* __restrict__ out) {
    __shared__ Smem S;
    int bid = blockIdx.x, b = bid >> 2, c = bid & 3;
    int tid = threadIdx.x, wid = tid >> 6, lane = tid & 63;
    int row0 = wid * 32;
    const float* Th = inp + (size_t)b * (N * N);
    const float* Rc = Rws + (size_t)c * (N * N);

    // r = full column `lane` of R (coalesced)
    f32x2 r[32];
#pragma unroll
    for (int k = 0; k < 32; ++k) {
        r[k].x = Rc[(2 * k) * N + lane];
        r[k].y = Rc[(2 * k + 1) * N + lane];
    }
    // U = Theta * R : rows [row0,row0+32), column `lane` -> LDS
#pragma clang loop unroll(disable)
    for (int i = 0; i < 32; ++i) {
        const float4* __restrict__ row = (const float4*)(Th + (size_t)(row0 + i) * N);
        f32x2 a = {0.f, 0.f}, bacc = {0.f, 0.f};
#pragma unroll
        for (int q = 0; q < 16; q += 2) {
            float4 v0 = row[q], v1 = row[q + 1];
            a    = (f32x2){v0.x, v0.y} * r[2 * q]     + a;
            a    = (f32x2){v0.z, v0.w} * r[2 * q + 1] + a;
            bacc = (f32x2){v1.x, v1.y} * r[2 * q + 2] + bacc;
            bacc = (f32x2){v1.z, v1.w} * r[2 * q + 3] + bacc;
        }
        f32x2 sres = a + bacc;
        S.mat[(row0 + i) * LSTR + lane] = sres.x + sres.y;
    }
    __syncthreads();
    // ucol = full column `lane` of U
    f32x2 ucol[32];
#pragma unroll
    for (int k = 0; k < 32; ++k) {
        ucol[k].x = S.mat[(2 * k) * LSTR + lane];
        ucol[k].y = S.mat[(2 * k + 1) * LSTR + lane];
    }
    __syncthreads();   // everyone done reading U before overwrite
    // M = R * U : rows [row0,+32), column `lane` -> overwrite LDS
#pragma clang loop unroll(disable)
    for (int i = 0; i < 32; ++i) {
        const float4* __restrict__ row = (const float4*)(Rc + (size_t)(row0 + i) * N);
        f32x2 a = {0.f, 0.f}, bacc = {0.f, 0.f};
#pragma unroll
        for (int q = 0; q < 16; q += 2) {
            float4 v0 = row[q], v1 = row[q + 1];
            a    = (f32x2){v0.x, v0.y} * ucol[2 * q]     + a;
            a    = (f32x2){v0.z, v0.w} * ucol[2 * q + 1] + a;
            bacc = (f32x2){v1.x, v1.y} * ucol[2 * q + 2] + bacc;
            bacc = (f32x2){v1.z, v1.w} * ucol[2 * q + 3] + bacc;
        }
        f32x2 sres = a + bacc;
        S.mat[(row0 + i) * LSTR + lane] = sres.x + sres.y;
    }
    __syncthreads();
    // g = 0.5*(M + M^T) half-column + convex recondition with identity
    f32x2 g[16];
#pragma unroll
    for (int i = 0; i < 16; ++i) {
        f32x2 own;
        own.x = S.mat[(row0 + 2 * i) * LSTR + lane];
        own.y = S.mat[(row0 + 2 * i + 1) * LSTR + lane];
        f32x2 tr = *(const f32x2*)&S.mat[lane * LSTR + row0 + 2 * i];
        f32x2 h = {0.5f, 0.5f};
        g[i] = h * (own + tr);
        g[i].x = 0.999f * g[i].x + ((row0 + 2 * i)     == lane ? 0.001f : 0.f);
        g[i].y = 0.999f * g[i].y + ((row0 + 2 * i + 1) == lane ? 0.001f : 0.f);
    }

    float d = jacobi_split(g, lane, wid, S, 15);
    float coef = 0.5f * logf(d) / d;   // f = log(lambda) = 0.5*log(d)
    recon_store(g, coef, lane, wid, S, out + (size_t)bid * (N * N));
}

extern "C" void kernel_launch(void* const* d_in, const int* in_sizes, int n_in,
                              void* d_out, int out_size, void* d_ws, size_t ws_size,
                              hipStream_t stream) {
    const float* inp = (const float*)d_in[0];   // [B,64,64] f32
    const float* wgt = (const float*)d_in[1];   // [C,64,64] f32
    float* out = (float*)d_out;                 // [B,C,64,64] f32
    float* Rws = (float*)d_ws;                  // C*64*64 floats scratch

    int B = in_sizes[0] / (N * N);
    int C = in_sizes[1] / (N * N);

    hipLaunchKernelGGL(prep_R, dim3(C), dim3(128), 0, stream, wgt, Rws);
    hipLaunchKernelGGL(tangent_log, dim3(B * C), dim3(128), 0, stream, inp, Rws, out);
}

// Round 6
// 5094.366 us; speedup vs baseline: 1.1619x; 1.1619x over previous
//
#include <hip/hip_runtime.h>
#include <math.h>

#define N 64
#define CSTR 68   // column stride (floats): 272B = 17*16B -> b128-aligned, bank-balanced

typedef float f32x2 __attribute__((ext_vector_type(2)));

struct __align__(16) Smem {
    float mat[N * CSTR];   // column-major: mat[c*CSTR + r] = M[r][c]
    float nbuf[2 * N];     // per-sweep norm partials
    f32x2 obuf[2][N];      // pair-dot partials (x=wave0, y=wave1), parity-buffered
};

__device__ __forceinline__ float bperm(int byteaddr, float v) {
    return __int_as_float(__builtin_amdgcn_ds_bpermute(byteaddr, __float_as_int(v)));
}
__device__ __forceinline__ float rlane(float v, int k) {   // uniform k -> v_readlane (VALU)
    return __int_as_float(__builtin_amdgcn_readlane(__float_as_int(v), k));
}
__device__ __forceinline__ float dot4(float4 a, float4 b) {
    return fmaf(a.x, b.x, fmaf(a.y, b.y, fmaf(a.z, b.z, a.w * b.w)));
}

// One-sided Jacobi; matrix columns live in LDS (column-major, stride CSTR).
// Wave w owns rows [32w,32w+32): lane j holds that half of column j in g[8].
// Partner-column halves fetched via ds_read_b128 (16B/lane/inst, ~4x bpermute
// bandwidth); updated halves written back the same way. Each wave touches only
// its own row range, so no cross-wave LDS hazard in the loop; pair dots are
// completed via obuf partials with both waves summing in the same order ->
// o/d/c/s streams bitwise-identical -> uniform branches.
__device__ float jacobi_b128(float4 (&g)[8], int lane, int wid, Smem& S, int max_sweeps) {
    float4* ownc = (float4*)&S.mat[lane * CSTR + 32 * wid];
    float d = 0.f;
#pragma clang loop unroll(disable)
    for (int s = 0; s < max_sweeps; ++s) {
        float nh = 0.f;
#pragma unroll
        for (int i = 0; i < 8; ++i) nh += dot4(g[i], g[i]);
        S.nbuf[wid * N + lane] = nh;
        __syncthreads();
        d = S.nbuf[lane] + S.nbuf[N + lane];
        int anybad = 0;
#pragma clang loop unroll(disable)
        for (int m = 1; m < N; ++m) {
            const float4* pc = (const float4*)&S.mat[(lane ^ m) * CSTR + 32 * wid];
            float4 t[8];
#pragma unroll
            for (int i = 0; i < 8; ++i) t[i] = pc[i];
            float op = 0.f;
#pragma unroll
            for (int i = 0; i < 8; ++i) op += dot4(g[i], t[i]);
            float doth = bperm((lane ^ m) << 2, d);
            int p = m & 1;
            ((float*)&S.obuf[p][lane])[wid] = op;
            __syncthreads();
            f32x2 ov = S.obuf[p][lane];
            float o = ov.x + ov.y;           // same order on both waves
            bool is_lo = lane < (lane ^ m);
            float dp = is_lo ? d : doth;
            float dq = is_lo ? doth : d;
            int roundbad = __any(o * o > 1e-11f * dp * dq);
            anybad |= roundbad;
            if (!roundbad) continue;         // uniform: converged round, no write-back
            bool skip = (o * o) <= (1e-24f * dp * dq);
            float osafe = skip ? 1.0f : o;
            float theta = (dq - dp) / (2.0f * osafe);
            float tt = -copysignf(1.0f, theta) /
                       (fabsf(theta) + sqrtf(fmaf(theta, theta, 1.0f)));
            float cc = rsqrtf(fmaf(tt, tt, 1.0f));
            float sv = tt * cc;
            cc = skip ? 1.0f : cc;
            sv = skip ? 0.0f : sv;
            float c2 = cc * cc, s2 = sv * sv, cso = 2.0f * cc * sv * o;
            d = is_lo ? fmaf(c2, dp, fmaf(s2, dq, cso))
                      : fmaf(s2, dp, fmaf(c2, dq, -cso));
            d = fmaxf(d, 1e-30f);
            float ss = is_lo ? sv : -sv;
#pragma unroll
            for (int i = 0; i < 8; ++i) {
                g[i].x = fmaf(ss, t[i].x, cc * g[i].x);
                g[i].y = fmaf(ss, t[i].y, cc * g[i].y);
                g[i].z = fmaf(ss, t[i].z, cc * g[i].z);
                g[i].w = fmaf(ss, t[i].w, cc * g[i].w);
            }
#pragma unroll
            for (int i = 0; i < 8; ++i) ownc[i] = g[i];
        }
        if (!__any(anybad)) break;   // uniform across both waves
    }
    float nh = 0.f;
#pragma unroll
    for (int i = 0; i < 8; ++i) nh += dot4(g[i], g[i]);
    S.nbuf[wid * N + lane] = nh;
    __syncthreads();
    d = S.nbuf[lane] + S.nbuf[N + lane];
    return d;
}

// out rows [32w,+32), column `lane`: out = sum_k coef_k g_k g_k^T.
// All broadcasts via v_readlane (VALU pipe) -- only DS is the 64 b32 row reads.
__device__ void recon_store(const float4 (&g)[8], float coef, int lane, int wid,
                            Smem& S, float* __restrict__ outp) {
    int row0 = wid * 32;
    float4 acc[8];
#pragma unroll
    for (int i = 0; i < 8; ++i) acc[i] = (float4){0.f, 0.f, 0.f, 0.f};
#pragma clang loop unroll(disable)
    for (int k = 0; k < N; ++k) {
        float wk = rlane(coef, k) * S.mat[k * CSTR + lane];   // coef_k * G[lane][k]
#pragma unroll
        for (int i = 0; i < 8; ++i) {
            acc[i].x = fmaf(rlane(g[i].x, k), wk, acc[i].x);
            acc[i].y = fmaf(rlane(g[i].y, k), wk, acc[i].y);
            acc[i].z = fmaf(rlane(g[i].z, k), wk, acc[i].z);
            acc[i].w = fmaf(rlane(g[i].w, k), wk, acc[i].w);
        }
    }
#pragma unroll
    for (int i = 0; i < 8; ++i) {
        outp[(row0 + 4 * i + 0) * N + lane] = acc[i].x;
        outp[(row0 + 4 * i + 1) * N + lane] = acc[i].y;
        outp[(row0 + 4 * i + 2) * N + lane] = acc[i].z;
        outp[(row0 + 4 * i + 3) * N + lane] = acc[i].w;
    }
}

// Kernel A: R_c = ((1-psi) W_c + psi I)^{-1/2}; one block (2 waves) per channel.
__global__ __launch_bounds__(128, 4) void prep_R(const float* __restrict__ wgt,
                                                 float* __restrict__ Rws) {
    __shared__ Smem S;
    int c = blockIdx.x;
    int tid = threadIdx.x, wid = tid >> 6, lane = tid & 63;
    int row0 = wid * 32;
    const float* W = wgt + (size_t)c * (N * N);
    float4 g[8];
#pragma unroll
    for (int i = 0; i < 8; ++i) {
        float v[4];
#pragma unroll
        for (int q = 0; q < 4; ++q) {
            int rr = row0 + 4 * i + q;
            v[q] = 0.999f * W[rr * N + lane] + (rr == lane ? 0.001f : 0.f);
        }
        g[i] = (float4){v[0], v[1], v[2], v[3]};
    }
    float4* ownc = (float4*)&S.mat[lane * CSTR + row0];
#pragma unroll
    for (int i = 0; i < 8; ++i) ownc[i] = g[i];
    float d = jacobi_b128(g, lane, wid, S, 15);
    float coef = sqrtf(rsqrtf(d)) / d;   // f = lambda^{-1/2} -> coef = d^{-5/4}
    recon_store(g, coef, lane, wid, S, Rws + (size_t)c * (N * N));
}

// Kernel B: per (b,c): M = R_c Theta_b R_c -> symmetrize -> recondition -> log.
__global__ __launch_bounds__(128, 4) void tangent_log(const float* __restrict__ inp,
                                                      const float* __restrict__ Rws,
                                                      float* __restrict__ out) {
    __shared__ Smem S;
    int bid = blockIdx.x, b = bid >> 2, c = bid & 3;
    int tid = threadIdx.x, wid = tid >> 6, lane = tid & 63;
    int row0 = wid * 32;
    const float* Th = inp + (size_t)b * (N * N);
    const float* Rc = Rws + (size_t)c * (N * N);

    // r = full column `lane` of R (coalesced b32 loads)
    f32x2 r[32];
#pragma unroll
    for (int k = 0; k < 32; ++k) {
        r[k].x = Rc[(2 * k) * N + lane];
        r[k].y = Rc[(2 * k + 1) * N + lane];
    }
    // U = Theta * R : rows [row0,+32), column `lane` -> LDS (column-major)
#pragma clang loop unroll(disable)
    for (int i = 0; i < 32; ++i) {
        const float4* __restrict__ row = (const float4*)(Th + (size_t)(row0 + i) * N);
        f32x2 a = {0.f, 0.f}, bacc = {0.f, 0.f};
#pragma unroll
        for (int q = 0; q < 16; q += 2) {
            float4 v0 = row[q], v1 = row[q + 1];
            a    = (f32x2){v0.x, v0.y} * r[2 * q]     + a;
            a    = (f32x2){v0.z, v0.w} * r[2 * q + 1] + a;
            bacc = (f32x2){v1.x, v1.y} * r[2 * q + 2] + bacc;
            bacc = (f32x2){v1.z, v1.w} * r[2 * q + 3] + bacc;
        }
        f32x2 sres = a + bacc;
        S.mat[lane * CSTR + row0 + i] = sres.x + sres.y;
    }
    __syncthreads();
    // ucol = full column `lane` of U (contiguous in column-major -> b128 reads)
    f32x2 ucol[32];
    {
        const f32x2* myc = (const f32x2*)&S.mat[lane * CSTR];
#pragma unroll
        for (int k = 0; k < 32; ++k) ucol[k] = myc[k];
    }
    __syncthreads();   // all U reads done before overwrite
    // M = R * U : rows [row0,+32), column `lane` -> overwrite LDS
#pragma clang loop unroll(disable)
    for (int i = 0; i < 32; ++i) {
        const float4* __restrict__ row = (const float4*)(Rc + (size_t)(row0 + i) * N);
        f32x2 a = {0.f, 0.f}, bacc = {0.f, 0.f};
#pragma unroll
        for (int q = 0; q < 16; q += 2) {
            float4 v0 = row[q], v1 = row[q + 1];
            a    = (f32x2){v0.x, v0.y} * ucol[2 * q]     + a;
            a    = (f32x2){v0.z, v0.w} * ucol[2 * q + 1] + a;
            bacc = (f32x2){v1.x, v1.y} * ucol[2 * q + 2] + bacc;
            bacc = (f32x2){v1.z, v1.w} * ucol[2 * q + 3] + bacc;
        }
        f32x2 sres = a + bacc;
        S.mat[lane * CSTR + row0 + i] = sres.x + sres.y;
    }
    __syncthreads();
    // g = 0.5*(M + M^T) half-column + convex recondition
    float4 g[8];
    {
        float4 own[8];
        const float4* oc = (const float4*)&S.mat[lane * CSTR + row0];
#pragma unroll
        for (int i = 0; i < 8; ++i) own[i] = oc[i];
        float tr[32];
#pragma unroll
        for (int i = 0; i < 32; ++i) tr[i] = S.mat[(row0 + i) * CSTR + lane];  // M[lane][row0+i]
        __syncthreads();   // all reads done before write-back
#pragma unroll
        for (int i = 0; i < 8; ++i) {
            float v[4];
#pragma unroll
            for (int q = 0; q < 4; ++q) {
                int rr = row0 + 4 * i + q;
                float ov = (q == 0) ? own[i].x : (q == 1) ? own[i].y : (q == 2) ? own[i].z : own[i].w;
                float sym = 0.5f * (ov + tr[4 * i + q]);
                v[q] = 0.999f * sym + (rr == lane ? 0.001f : 0.f);
            }
            g[i] = (float4){v[0], v[1], v[2], v[3]};
        }
        float4* wc = (float4*)&S.mat[lane * CSTR + row0];
#pragma unroll
        for (int i = 0; i < 8; ++i) wc[i] = g[i];
    }

    float d = jacobi_b128(g, lane, wid, S, 15);
    float coef = 0.5f * logf(d) / d;   // f = log(lambda) = 0.5*log(d)
    recon_store(g, coef, lane, wid, S, out + (size_t)bid * (N * N));
}

extern "C" void kernel_launch(void* const* d_in, const int* in_sizes, int n_in,
                              void* d_out, int out_size, void* d_ws, size_t ws_size,
                              hipStream_t stream) {
    const float* inp = (const float*)d_in[0];   // [B,64,64] f32
    const float* wgt = (const float*)d_in[1];   // [C,64,64] f32
    float* out = (float*)d_out;                 // [B,C,64,64] f32
    float* Rws = (float*)d_ws;                  // C*64*64 floats scratch

    int B = in_sizes[0] / (N * N);
    int C = in_sizes[1] / (N * N);

    hipLaunchKernelGGL(prep_R, dim3(C), dim3(128), 0, stream, wgt, Rws);
    hipLaunchKernelGGL(tangent_log, dim3(B * C), dim3(128), 0, stream, inp, Rws, out);
}